// Round 8
// baseline (226.455 us; speedup 1.0000x reference)
//
#include <hip/hip_runtime.h>
#include <cmath>

// LinearAttention round 8.
// vs r7: attn4 — one wave per head (8 waves/block), ctx in LDS (broadcast reads),
// 2x wave parallelism; gemm16 staging via global_load_lds width=16 (no VGPR round trip).

#define B 4
#define C 256
#define Hh 128
#define Wd 128
#define HW (Hh*Wd)
#define HEADS 8
#define HD 32
#define OSCALE 256.0f
#define NSP 16

typedef _Float16 half_t;
typedef _Float16 f16x8 __attribute__((ext_vector_type(8)));
typedef float f32x4 __attribute__((ext_vector_type(4)));

__device__ __forceinline__ void gload_lds16(const half_t* g, half_t* l) {
  __builtin_amdgcn_global_load_lds((const __attribute__((address_space(1))) void*)g,
                                   (__attribute__((address_space(3))) void*)l, 16, 0, 0);
}

// ---------------- all weights fp32 -> fp16, one launch ----------------
__global__ __launch_bounds__(256) void wcvt_all(const float* __restrict__ wq1,
                                                const float* __restrict__ wk1,
                                                const float* __restrict__ wv1,
                                                const float* __restrict__ wout,
                                                half_t* __restrict__ Wh,
                                                half_t* __restrict__ Woh) {
  int i = blockIdx.x * 256 + threadIdx.x;  // grid 1024 -> 262144
  if (i < 65536) Wh[i] = (half_t)wq1[i];
  else if (i < 131072) Wh[i] = (half_t)wk1[i - 65536];
  else if (i < 196608) Wh[i] = (half_t)wv1[i - 131072];
  else Woh[i - 196608] = (half_t)wout[i - 196608];
}

// ---------------- channel LayerNorm -> X_h[b][pix][c] fp16 ----------------
__global__ __launch_bounds__(256) void ln2(const float* __restrict__ fmap,
                                           const float* __restrict__ g,
                                           half_t* __restrict__ Xh) {
  int b = blockIdx.y;
  int lane = threadIdx.x & 63;
  int gq = threadIdx.x >> 6;               // 0..3 channel group
  int px = blockIdx.x * 64 + lane;
  __shared__ float gs[C];
  __shared__ float sm1[4][64], sm2[4][64];
  gs[threadIdx.x] = g[threadIdx.x];
  const float* fp = fmap + ((size_t)b * C + gq * 64) * HW + px;
  float vbuf[64];
  float s = 0.f, s2 = 0.f;
#pragma unroll
  for (int j = 0; j < 64; ++j) {
    float v = fp[(size_t)j * HW];
    vbuf[j] = v;
    s += v; s2 = fmaf(v, v, s2);
  }
  sm1[gq][lane] = s; sm2[gq][lane] = s2;
  __syncthreads();
  float st = 0.f, st2 = 0.f;
#pragma unroll
  for (int q = 0; q < 4; ++q) { st += sm1[q][lane]; st2 += sm2[q][lane]; }
  float mean = st * (1.f / C);
  float var = st2 * (1.f / C) - mean * mean;
  float rstd = rsqrtf(var + 1e-5f);
  half_t* xp = Xh + ((size_t)b * HW + px) * 256 + gq * 64;
#pragma unroll
  for (int j0 = 0; j0 < 64; j0 += 8) {
    f16x8 v8;
#pragma unroll
    for (int jj = 0; jj < 8; ++jj)
      v8[jj] = (half_t)((vbuf[j0 + jj] - mean) * rstd * gs[gq * 64 + j0 + jj]);
    *(f16x8*)(xp + j0) = v8;
  }
}

// ---------------- fp16 MFMA GEMM, global_load_lds staging ----------------
template<int MODE>
__global__ __launch_bounds__(256) void gemm16(const half_t* __restrict__ Xh,
                                              const half_t* __restrict__ Wh,
                                              half_t* __restrict__ Yh,
                                              float* __restrict__ Yf) {
  __shared__ half_t Xs[2][128 * 64];
  __shared__ half_t Ws[2][128 * 64];
  const int tid = threadIdx.x;
  const int wave = tid >> 6, lane = tid & 63;
  const int lr = lane & 15, lq = lane >> 4;
  const int b = blockIdx.z;
  const int pix0 = blockIdx.x * 128;
  const int m0 = blockIdx.y * 128;
  const int wm = wave >> 1, wn = wave & 1;

  const half_t* xb = Xh + ((size_t)b * HW + pix0) * 256;
  const half_t* wb = Wh + (size_t)m0 * 256;

  f32x4 acc[4][4];
#pragma unroll
  for (int i = 0; i < 4; ++i)
#pragma unroll
    for (int j = 0; j < 4; ++j) { f32x4 z = {0.f, 0.f, 0.f, 0.f}; acc[i][j] = z; }

  // stage K-chunk 0 into buf 0 (async, drained by __syncthreads)
#pragma unroll
  for (int it = 0; it < 4; ++it) {
    int e = it * 256 + tid, r = e >> 3, c = e & 7;
    int go = (c ^ (r & 7)) << 3;            // inverse-swizzled SOURCE, linear dest
    gload_lds16(xb + (size_t)r * 256 + go, &Xs[0][e * 8]);
    gload_lds16(wb + (size_t)r * 256 + go, &Ws[0][e * 8]);
  }
  __syncthreads();

  for (int kk = 0; kk < 4; ++kk) {
    int buf = kk & 1;
    if (kk < 3) {  // async-stage next chunk into other buffer before compute
#pragma unroll
      for (int it = 0; it < 4; ++it) {
        int e = it * 256 + tid, r = e >> 3, c = e & 7;
        int go = (kk + 1) * 64 + ((c ^ (r & 7)) << 3);
        gload_lds16(xb + (size_t)r * 256 + go, &Xs[buf ^ 1][e * 8]);
        gload_lds16(wb + (size_t)r * 256 + go, &Ws[buf ^ 1][e * 8]);
      }
    }
#pragma unroll
    for (int kf = 0; kf < 2; ++kf) {
      f16x8 afr[4], bfr[4];
#pragma unroll
      for (int mf = 0; mf < 4; ++mf) {
        int r = wm * 64 + mf * 16 + lr;
        int q = kf * 4 + lq;
        afr[mf] = *(const f16x8*)&Ws[buf][r * 64 + ((q ^ (r & 7)) << 3)];  // swz READ
      }
#pragma unroll
      for (int nf = 0; nf < 4; ++nf) {
        int r = wn * 64 + nf * 16 + lr;
        int q = kf * 4 + lq;
        bfr[nf] = *(const f16x8*)&Xs[buf][r * 64 + ((q ^ (r & 7)) << 3)];
      }
#pragma unroll
      for (int mf = 0; mf < 4; ++mf)
#pragma unroll
        for (int nf = 0; nf < 4; ++nf)
          acc[mf][nf] = __builtin_amdgcn_mfma_f32_16x16x32_f16(afr[mf], bfr[nf], acc[mf][nf], 0, 0, 0);
    }
    __syncthreads();  // drains vmcnt (next-buf loads) + lgkm before buffer swap
  }

  const int msb = m0 + wm * 64;
  const int pixb = pix0 + wn * 64 + lr;
#pragma unroll
  for (int mf = 0; mf < 4; ++mf) {
    int ms = msb + mf * 16 + lq * 4;
#pragma unroll
    for (int nf = 0; nf < 4; ++nf) {
      int pp = pixb + nf * 16;
      if constexpr (MODE == 0) {
        int w = ms >> 8;
        int oc = ms & 255;
        half_t* dst = Yh + (size_t)w * ((size_t)B * C * HW) + ((size_t)b * C + oc) * HW + pp;
#pragma unroll
        for (int j = 0; j < 4; ++j) dst[(size_t)j * HW] = (half_t)acc[mf][nf][j];
      } else {
        float* dst = Yf + ((size_t)b * C + ms) * HW + pp;
#pragma unroll
        for (int j = 0; j < 4; ++j) dst[(size_t)j * HW] = acc[mf][nf][j] * (1.0f / OSCALE);
      }
    }
  }
}

// ---------------- vectorized depthwise 3x3, SAME pad ----------------
// MODE 0: fp32 out; MODE 1: fp16 out; MODE 2: fp16 exp(out) (K path).
template<int MODE>
__global__ __launch_bounds__(256) void dw3x3_v(const half_t* __restrict__ Yin,
                                               const float* __restrict__ W2,
                                               void* __restrict__ Zv) {
  int c = blockIdx.y, b = blockIdx.z;
  int r = threadIdx.x >> 4;
  int j0 = (threadIdx.x & 15) * 8;
  int i = blockIdx.x * 16 + r;
  const half_t* plane = Yin + ((size_t)(b * C + c)) * HW;
  float w[9];
#pragma unroll
  for (int k = 0; k < 9; ++k) w[k] = W2[c * 9 + k];
  float acc[8];
#pragma unroll
  for (int p = 0; p < 8; ++p) acc[p] = 0.f;
#pragma unroll
  for (int dr = 0; dr < 3; ++dr) {
    int ii = i + dr - 1;
    if (ii < 0 || ii >= Hh) continue;
    const half_t* rp = plane + ii * Wd + j0;
    f16x8 cv = *(const f16x8*)rp;
    float lv = (j0 > 0) ? (float)rp[-1] : 0.f;
    float rv = (j0 + 8 < Wd) ? (float)rp[8] : 0.f;
    float cf[8];
#pragma unroll
    for (int p = 0; p < 8; ++p) cf[p] = (float)cv[p];
    float w0 = w[dr * 3], w1 = w[dr * 3 + 1], w2v = w[dr * 3 + 2];
#pragma unroll
    for (int p = 0; p < 8; ++p) {
      float l = (p == 0) ? lv : cf[p - 1];
      float rr = (p == 7) ? rv : cf[p + 1];
      acc[p] = fmaf(w0, l, acc[p]);
      acc[p] = fmaf(w1, cf[p], acc[p]);
      acc[p] = fmaf(w2v, rr, acc[p]);
    }
  }
  size_t off = ((size_t)(b * C + c)) * HW + i * Wd + j0;
  if constexpr (MODE == 1 || MODE == 2) {
    f16x8 o8;
#pragma unroll
    for (int p = 0; p < 8; ++p)
      o8[p] = (half_t)(MODE == 2 ? expf(acc[p]) : acc[p]);
    *(f16x8*)((half_t*)Zv + off) = o8;
  } else {
    float* op = (float*)Zv + off;
    *(float4*)op = make_float4(acc[0], acc[1], acc[2], acc[3]);
    *(float4*)(op + 4) = make_float4(acc[4], acc[5], acc[6], acc[7]);
  }
}

// ---------------- sum of ek per (b,c) row -> Sk ----------------
__global__ __launch_bounds__(256) void ksum(const half_t* __restrict__ EK,
                                            float* __restrict__ Sk) {
  int c = blockIdx.x, b = blockIdx.y;
  const half_t* p = EK + ((size_t)(b * C + c)) * HW;
  int t = threadIdx.x;
  float s = 0.f;
  for (int i = t * 8; i < HW; i += 2048) {
    f16x8 v = *(const f16x8*)(p + i);
#pragma unroll
    for (int j = 0; j < 8; ++j) s += (float)v[j];
  }
  __shared__ float red[256];
  red[t] = s; __syncthreads();
  for (int st = 128; st > 0; st >>= 1) {
    if (t < st) red[t] += red[t + st];
    __syncthreads();
  }
  if (t == 0) Sk[b * C + c] = red[0];
}

// ---------------- ctx_raw = EK @ V^T per head, pure MFMA ----------------
__global__ __launch_bounds__(256) void ctx_mfma(const half_t* __restrict__ EK,
                                                const half_t* __restrict__ V,
                                                float* __restrict__ part) {
  int bh = blockIdx.x, sp = blockIdx.y;
  int wave = threadIdx.x >> 6, lane = threadIdx.x & 63;
  int lr = lane & 15, lq = lane >> 4;
  const size_t base = (size_t)bh * HD * HW;
  const half_t* ekp = EK + base + (size_t)lr * HW;
  const half_t* vp  = V  + base + (size_t)lr * HW;
  f32x4 a00 = {0.f,0.f,0.f,0.f}, a01 = a00, a10 = a00, a11 = a00;
  const int n0w = sp * 1024 + wave * 256 + lq * 8;
#pragma unroll
  for (int ks = 0; ks < 8; ++ks) {
    int n = n0w + ks * 32;
    f16x8 fa0 = *(const f16x8*)(ekp + n);
    f16x8 fa1 = *(const f16x8*)(ekp + (size_t)16 * HW + n);
    f16x8 fb0 = *(const f16x8*)(vp + n);
    f16x8 fb1 = *(const f16x8*)(vp + (size_t)16 * HW + n);
    a00 = __builtin_amdgcn_mfma_f32_16x16x32_f16(fa0, fb0, a00, 0, 0, 0);
    a01 = __builtin_amdgcn_mfma_f32_16x16x32_f16(fa0, fb1, a01, 0, 0, 0);
    a10 = __builtin_amdgcn_mfma_f32_16x16x32_f16(fa1, fb0, a10, 0, 0, 0);
    a11 = __builtin_amdgcn_mfma_f32_16x16x32_f16(fa1, fb1, a11, 0, 0, 0);
  }
  __shared__ float red[4][1024];
#pragma unroll
  for (int j = 0; j < 4; ++j) {
    int dlo = lq * 4 + j;
    red[wave][(dlo)      * 32 + lr]      = a00[j];
    red[wave][(dlo)      * 32 + 16 + lr] = a01[j];
    red[wave][(dlo + 16) * 32 + lr]      = a10[j];
    red[wave][(dlo + 16) * 32 + 16 + lr] = a11[j];
  }
  __syncthreads();
  float* pp = part + ((size_t)sp * 32 + bh) * 1024;
  for (int idx = threadIdx.x; idx < 1024; idx += 256)
    pp[idx] = red[0][idx] + red[1][idx] + red[2][idx] + red[3][idx];
}

// ---------------- reduce ctx partials, apply 1/S ----------------
__global__ __launch_bounds__(256) void ctxred(const float* __restrict__ part,
                                              const float* __restrict__ Sk,
                                              float* __restrict__ ctx) {
  int bh = blockIdx.x;
  int t = threadIdx.x;
  for (int idx = t; idx < 1024; idx += 256) {
    int d = idx >> 5;
    float s = 0.f;
#pragma unroll
    for (int sp = 0; sp < NSP; ++sp) s += part[((size_t)sp * 32 + bh) * 1024 + idx];
    ctx[(size_t)bh * 1024 + idx] = s / Sk[bh * HD + d];
  }
}

// ---------------- fused: no-max q-softmax -> @ctx(LDS) -> SiLU -> Oh fp16 ----------------
// block 512 = 8 waves, wave w = head w, 64 px per block; ctx staged in LDS.
__global__ __launch_bounds__(512) void attn4(const half_t* __restrict__ Qh,
                                             const float* __restrict__ ctx,
                                             half_t* __restrict__ Oh) {
  int b = blockIdx.y;
  int lane = threadIdx.x & 63;
  int h = __builtin_amdgcn_readfirstlane(threadIdx.x >> 6);
  int px = blockIdx.x * 64 + lane;
  __shared__ float cs[HEADS * 1024];
  {
    const float4* src = (const float4*)(ctx + ((size_t)b * HEADS) * 1024);
    float4* dst = (float4*)cs;
    for (int i = threadIdx.x; i < HEADS * 256; i += 512) dst[i] = src[i];
  }
  __syncthreads();
  const half_t* qp = Qh + ((size_t)(b * C + h * HD)) * HW + px;
  const float* cw = cs + h * 1024;  // wave-uniform LDS base -> broadcast reads
  float acc[HD];
#pragma unroll
  for (int e = 0; e < HD; ++e) acc[e] = 0.f;
  float s = 0.f;
#pragma unroll
  for (int d = 0; d < HD; ++d) {
    float ev = expf((float)qp[(size_t)d * HW]);   // logits bounded: no max pass
    s += ev;
#pragma unroll
    for (int e4 = 0; e4 < 8; ++e4) {
      float4 c4 = *(const float4*)(cw + d * HD + e4 * 4);  // LDS broadcast
      acc[e4 * 4 + 0] = fmaf(ev, c4.x, acc[e4 * 4 + 0]);
      acc[e4 * 4 + 1] = fmaf(ev, c4.y, acc[e4 * 4 + 1]);
      acc[e4 * 4 + 2] = fmaf(ev, c4.z, acc[e4 * 4 + 2]);
      acc[e4 * 4 + 3] = fmaf(ev, c4.w, acc[e4 * 4 + 3]);
    }
  }
  float inv = 0.1767766952966369f / s;  // 32^-0.5 / s
  half_t* op = Oh + ((size_t)b * HW + px) * 256 + h * HD;
#pragma unroll
  for (int e0 = 0; e0 < HD; e0 += 8) {
    f16x8 v8;
#pragma unroll
    for (int j = 0; j < 8; ++j) {
      float a = acc[e0 + j] * inv;
      float sg = 1.f / (1.f + expf(-a));
      v8[j] = (half_t)(a * sg * OSCALE);
    }
    *(f16x8*)(op + e0) = v8;
  }
}

extern "C" void kernel_launch(void* const* d_in, const int* in_sizes, int n_in,
                              void* d_out, int out_size, void* d_ws, size_t ws_size,
                              hipStream_t stream) {
  const float* fmap = (const float*)d_in[0];
  const float* g    = (const float*)d_in[1];
  const float* wq1  = (const float*)d_in[2];
  const float* wq2  = (const float*)d_in[3];
  const float* wk1  = (const float*)d_in[4];
  const float* wk2  = (const float*)d_in[5];
  const float* wv1  = (const float*)d_in[6];
  const float* wv2  = (const float*)d_in[7];
  const float* wout = (const float*)d_in[8];
  float* out = (float*)d_out;
  char* ws = (char*)d_ws;

  const size_t SZ = (size_t)B * C * HW;
  const size_t Mi = (size_t)1 << 20;
  // layout (byte offsets), live ranges audited:
  half_t* Xh   = (half_t*)(ws);                  // [0,32Mi)    ln2 -> gemm<0>
  half_t* Yh   = (half_t*)(ws + 32 * Mi);        // [32,128Mi)  Yq|Yk|Yv fp16
  half_t* Qh   = (half_t*)(ws + 128 * Mi);       // [128,160Mi) dwQ -> attn4
  half_t* EK   = (half_t*)(ws);                  // [0,32Mi)    exp(k) fp16 (Xh dead)
  half_t* Vh   = (half_t*)out;                   // d_out as fp16 V until ctx_mfma done
  float*  part = (float*)(ws + 96 * Mi);         // [96,98Mi)   over dead Yv
  float*  Sk   = (float*)(ws + 99 * Mi);         // 4KB
  float*  ctxb = (float*)(ws + 100 * Mi);        // 128KB
  half_t* Wh   = (half_t*)(ws + 192 * Mi);
  half_t* Woh  = (half_t*)(ws + 192 * Mi + 512 * 1024);
  half_t* Oh   = (half_t*)(ws + 32 * Mi);        // over dead Yq

  wcvt_all<<<dim3(1024), 256, 0, stream>>>(wq1, wk1, wv1, wout, Wh, Woh);

  ln2<<<dim3(HW / 64, B), 256, 0, stream>>>(fmap, g, Xh);

  gemm16<0><<<dim3(HW / 128, 6, B), 256, 0, stream>>>(Xh, Wh, Yh, nullptr);

  dw3x3_v<1><<<dim3(Hh / 16, C, B), 256, 0, stream>>>(Yh, wq2, Qh);            // Q fp16
  dw3x3_v<2><<<dim3(Hh / 16, C, B), 256, 0, stream>>>(Yh + SZ, wk2, EK);       // exp(K) fp16
  dw3x3_v<1><<<dim3(Hh / 16, C, B), 256, 0, stream>>>(Yh + 2 * SZ, wv2, Vh);   // V fp16

  ksum<<<dim3(C, B), 256, 0, stream>>>(EK, Sk);

  ctx_mfma<<<dim3(HEADS * B, NSP), 256, 0, stream>>>(EK, Vh, part);
  ctxred<<<dim3(32), 256, 0, stream>>>(part, Sk, ctxb);

  attn4<<<dim3(HW / 64, B), 512, 0, stream>>>(Qh, ctxb, Oh);

  gemm16<1><<<dim3(HW / 128, 2, B), 256, 0, stream>>>(Oh, Woh, nullptr, out);
}

// Round 9
// 211.827 us; speedup vs baseline: 1.0691x; 1.0691x over previous
//
#include <hip/hip_runtime.h>
#include <cmath>

// LinearAttention round 9.
// vs r8: attn5 — P@ctx via MFMA. ctx stored fp16 transposed [e][d] (B-frags in regs),
// P' built in-register (strided q loads + exp + shfl row-sum), SiLU epilogue through
// a swizzled 32KB LDS tile -> coalesced f16x8 stores. Replaces LDS-broadcast attn4
// (which was LDS-throughput-bound: 256 ds_read_b128/thread).

#define B 4
#define C 256
#define Hh 128
#define Wd 128
#define HW (Hh*Wd)
#define HEADS 8
#define HD 32
#define OSCALE 256.0f
#define NSP 16

typedef _Float16 half_t;
typedef _Float16 f16x8 __attribute__((ext_vector_type(8)));
typedef float f32x4 __attribute__((ext_vector_type(4)));

__device__ __forceinline__ void gload_lds16(const half_t* g, half_t* l) {
  __builtin_amdgcn_global_load_lds((const __attribute__((address_space(1))) void*)g,
                                   (__attribute__((address_space(3))) void*)l, 16, 0, 0);
}

// ---------------- all weights fp32 -> fp16, one launch ----------------
__global__ __launch_bounds__(256) void wcvt_all(const float* __restrict__ wq1,
                                                const float* __restrict__ wk1,
                                                const float* __restrict__ wv1,
                                                const float* __restrict__ wout,
                                                half_t* __restrict__ Wh,
                                                half_t* __restrict__ Woh) {
  int i = blockIdx.x * 256 + threadIdx.x;  // grid 1024 -> 262144
  if (i < 65536) Wh[i] = (half_t)wq1[i];
  else if (i < 131072) Wh[i] = (half_t)wk1[i - 65536];
  else if (i < 196608) Wh[i] = (half_t)wv1[i - 131072];
  else Woh[i - 196608] = (half_t)wout[i - 196608];
}

// ---------------- channel LayerNorm -> X_h[b][pix][c] fp16 ----------------
__global__ __launch_bounds__(256) void ln2(const float* __restrict__ fmap,
                                           const float* __restrict__ g,
                                           half_t* __restrict__ Xh) {
  int b = blockIdx.y;
  int lane = threadIdx.x & 63;
  int gq = threadIdx.x >> 6;               // 0..3 channel group
  int px = blockIdx.x * 64 + lane;
  __shared__ float gs[C];
  __shared__ float sm1[4][64], sm2[4][64];
  gs[threadIdx.x] = g[threadIdx.x];
  const float* fp = fmap + ((size_t)b * C + gq * 64) * HW + px;
  float vbuf[64];
  float s = 0.f, s2 = 0.f;
#pragma unroll
  for (int j = 0; j < 64; ++j) {
    float v = fp[(size_t)j * HW];
    vbuf[j] = v;
    s += v; s2 = fmaf(v, v, s2);
  }
  sm1[gq][lane] = s; sm2[gq][lane] = s2;
  __syncthreads();
  float st = 0.f, st2 = 0.f;
#pragma unroll
  for (int q = 0; q < 4; ++q) { st += sm1[q][lane]; st2 += sm2[q][lane]; }
  float mean = st * (1.f / C);
  float var = st2 * (1.f / C) - mean * mean;
  float rstd = rsqrtf(var + 1e-5f);
  half_t* xp = Xh + ((size_t)b * HW + px) * 256 + gq * 64;
#pragma unroll
  for (int j0 = 0; j0 < 64; j0 += 8) {
    f16x8 v8;
#pragma unroll
    for (int jj = 0; jj < 8; ++jj)
      v8[jj] = (half_t)((vbuf[j0 + jj] - mean) * rstd * gs[gq * 64 + j0 + jj]);
    *(f16x8*)(xp + j0) = v8;
  }
}

// ---------------- fp16 MFMA GEMM, global_load_lds staging ----------------
template<int MODE>
__global__ __launch_bounds__(256) void gemm16(const half_t* __restrict__ Xh,
                                              const half_t* __restrict__ Wh,
                                              half_t* __restrict__ Yh,
                                              float* __restrict__ Yf) {
  __shared__ half_t Xs[2][128 * 64];
  __shared__ half_t Ws[2][128 * 64];
  const int tid = threadIdx.x;
  const int wave = tid >> 6, lane = tid & 63;
  const int lr = lane & 15, lq = lane >> 4;
  const int b = blockIdx.z;
  const int pix0 = blockIdx.x * 128;
  const int m0 = blockIdx.y * 128;
  const int wm = wave >> 1, wn = wave & 1;

  const half_t* xb = Xh + ((size_t)b * HW + pix0) * 256;
  const half_t* wb = Wh + (size_t)m0 * 256;

  f32x4 acc[4][4];
#pragma unroll
  for (int i = 0; i < 4; ++i)
#pragma unroll
    for (int j = 0; j < 4; ++j) { f32x4 z = {0.f, 0.f, 0.f, 0.f}; acc[i][j] = z; }

  // stage K-chunk 0 into buf 0 (async, drained by __syncthreads)
#pragma unroll
  for (int it = 0; it < 4; ++it) {
    int e = it * 256 + tid, r = e >> 3, c = e & 7;
    int go = (c ^ (r & 7)) << 3;            // inverse-swizzled SOURCE, linear dest
    gload_lds16(xb + (size_t)r * 256 + go, &Xs[0][e * 8]);
    gload_lds16(wb + (size_t)r * 256 + go, &Ws[0][e * 8]);
  }
  __syncthreads();

  for (int kk = 0; kk < 4; ++kk) {
    int buf = kk & 1;
    if (kk < 3) {  // async-stage next chunk into other buffer before compute
#pragma unroll
      for (int it = 0; it < 4; ++it) {
        int e = it * 256 + tid, r = e >> 3, c = e & 7;
        int go = (kk + 1) * 64 + ((c ^ (r & 7)) << 3);
        gload_lds16(xb + (size_t)r * 256 + go, &Xs[buf ^ 1][e * 8]);
        gload_lds16(wb + (size_t)r * 256 + go, &Ws[buf ^ 1][e * 8]);
      }
    }
#pragma unroll
    for (int kf = 0; kf < 2; ++kf) {
      f16x8 afr[4], bfr[4];
#pragma unroll
      for (int mf = 0; mf < 4; ++mf) {
        int r = wm * 64 + mf * 16 + lr;
        int q = kf * 4 + lq;
        afr[mf] = *(const f16x8*)&Ws[buf][r * 64 + ((q ^ (r & 7)) << 3)];  // swz READ
      }
#pragma unroll
      for (int nf = 0; nf < 4; ++nf) {
        int r = wn * 64 + nf * 16 + lr;
        int q = kf * 4 + lq;
        bfr[nf] = *(const f16x8*)&Xs[buf][r * 64 + ((q ^ (r & 7)) << 3)];
      }
#pragma unroll
      for (int mf = 0; mf < 4; ++mf)
#pragma unroll
        for (int nf = 0; nf < 4; ++nf)
          acc[mf][nf] = __builtin_amdgcn_mfma_f32_16x16x32_f16(afr[mf], bfr[nf], acc[mf][nf], 0, 0, 0);
    }
    __syncthreads();  // drains vmcnt (next-buf loads) + lgkm before buffer swap
  }

  const int msb = m0 + wm * 64;
  const int pixb = pix0 + wn * 64 + lr;
#pragma unroll
  for (int mf = 0; mf < 4; ++mf) {
    int ms = msb + mf * 16 + lq * 4;
#pragma unroll
    for (int nf = 0; nf < 4; ++nf) {
      int pp = pixb + nf * 16;
      if constexpr (MODE == 0) {
        int w = ms >> 8;
        int oc = ms & 255;
        half_t* dst = Yh + (size_t)w * ((size_t)B * C * HW) + ((size_t)b * C + oc) * HW + pp;
#pragma unroll
        for (int j = 0; j < 4; ++j) dst[(size_t)j * HW] = (half_t)acc[mf][nf][j];
      } else {
        float* dst = Yf + ((size_t)b * C + ms) * HW + pp;
#pragma unroll
        for (int j = 0; j < 4; ++j) dst[(size_t)j * HW] = acc[mf][nf][j] * (1.0f / OSCALE);
      }
    }
  }
}

// ---------------- vectorized depthwise 3x3, SAME pad ----------------
// MODE 0: fp32 out; MODE 1: fp16 out; MODE 2: fp16 exp(out) (K path).
template<int MODE>
__global__ __launch_bounds__(256) void dw3x3_v(const half_t* __restrict__ Yin,
                                               const float* __restrict__ W2,
                                               void* __restrict__ Zv) {
  int c = blockIdx.y, b = blockIdx.z;
  int r = threadIdx.x >> 4;
  int j0 = (threadIdx.x & 15) * 8;
  int i = blockIdx.x * 16 + r;
  const half_t* plane = Yin + ((size_t)(b * C + c)) * HW;
  float w[9];
#pragma unroll
  for (int k = 0; k < 9; ++k) w[k] = W2[c * 9 + k];
  float acc[8];
#pragma unroll
  for (int p = 0; p < 8; ++p) acc[p] = 0.f;
#pragma unroll
  for (int dr = 0; dr < 3; ++dr) {
    int ii = i + dr - 1;
    if (ii < 0 || ii >= Hh) continue;
    const half_t* rp = plane + ii * Wd + j0;
    f16x8 cv = *(const f16x8*)rp;
    float lv = (j0 > 0) ? (float)rp[-1] : 0.f;
    float rv = (j0 + 8 < Wd) ? (float)rp[8] : 0.f;
    float cf[8];
#pragma unroll
    for (int p = 0; p < 8; ++p) cf[p] = (float)cv[p];
    float w0 = w[dr * 3], w1 = w[dr * 3 + 1], w2v = w[dr * 3 + 2];
#pragma unroll
    for (int p = 0; p < 8; ++p) {
      float l = (p == 0) ? lv : cf[p - 1];
      float rr = (p == 7) ? rv : cf[p + 1];
      acc[p] = fmaf(w0, l, acc[p]);
      acc[p] = fmaf(w1, cf[p], acc[p]);
      acc[p] = fmaf(w2v, rr, acc[p]);
    }
  }
  size_t off = ((size_t)(b * C + c)) * HW + i * Wd + j0;
  if constexpr (MODE == 1 || MODE == 2) {
    f16x8 o8;
#pragma unroll
    for (int p = 0; p < 8; ++p)
      o8[p] = (half_t)(MODE == 2 ? expf(acc[p]) : acc[p]);
    *(f16x8*)((half_t*)Zv + off) = o8;
  } else {
    float* op = (float*)Zv + off;
    *(float4*)op = make_float4(acc[0], acc[1], acc[2], acc[3]);
    *(float4*)(op + 4) = make_float4(acc[4], acc[5], acc[6], acc[7]);
  }
}

// ---------------- sum of ek per (b,c) row -> Sk ----------------
__global__ __launch_bounds__(256) void ksum(const half_t* __restrict__ EK,
                                            float* __restrict__ Sk) {
  int c = blockIdx.x, b = blockIdx.y;
  const half_t* p = EK + ((size_t)(b * C + c)) * HW;
  int t = threadIdx.x;
  float s = 0.f;
  for (int i = t * 8; i < HW; i += 2048) {
    f16x8 v = *(const f16x8*)(p + i);
#pragma unroll
    for (int j = 0; j < 8; ++j) s += (float)v[j];
  }
  __shared__ float red[256];
  red[t] = s; __syncthreads();
  for (int st = 128; st > 0; st >>= 1) {
    if (t < st) red[t] += red[t + st];
    __syncthreads();
  }
  if (t == 0) Sk[b * C + c] = red[0];
}

// ---------------- ctx_raw = EK @ V^T per head, pure MFMA ----------------
__global__ __launch_bounds__(256) void ctx_mfma(const half_t* __restrict__ EK,
                                                const half_t* __restrict__ V,
                                                float* __restrict__ part) {
  int bh = blockIdx.x, sp = blockIdx.y;
  int wave = threadIdx.x >> 6, lane = threadIdx.x & 63;
  int lr = lane & 15, lq = lane >> 4;
  const size_t base = (size_t)bh * HD * HW;
  const half_t* ekp = EK + base + (size_t)lr * HW;
  const half_t* vp  = V  + base + (size_t)lr * HW;
  f32x4 a00 = {0.f,0.f,0.f,0.f}, a01 = a00, a10 = a00, a11 = a00;
  const int n0w = sp * 1024 + wave * 256 + lq * 8;
#pragma unroll
  for (int ks = 0; ks < 8; ++ks) {
    int n = n0w + ks * 32;
    f16x8 fa0 = *(const f16x8*)(ekp + n);
    f16x8 fa1 = *(const f16x8*)(ekp + (size_t)16 * HW + n);
    f16x8 fb0 = *(const f16x8*)(vp + n);
    f16x8 fb1 = *(const f16x8*)(vp + (size_t)16 * HW + n);
    a00 = __builtin_amdgcn_mfma_f32_16x16x32_f16(fa0, fb0, a00, 0, 0, 0);
    a01 = __builtin_amdgcn_mfma_f32_16x16x32_f16(fa0, fb1, a01, 0, 0, 0);
    a10 = __builtin_amdgcn_mfma_f32_16x16x32_f16(fa1, fb0, a10, 0, 0, 0);
    a11 = __builtin_amdgcn_mfma_f32_16x16x32_f16(fa1, fb1, a11, 0, 0, 0);
  }
  __shared__ float red[4][1024];
#pragma unroll
  for (int j = 0; j < 4; ++j) {
    int dlo = lq * 4 + j;
    red[wave][(dlo)      * 32 + lr]      = a00[j];
    red[wave][(dlo)      * 32 + 16 + lr] = a01[j];
    red[wave][(dlo + 16) * 32 + lr]      = a10[j];
    red[wave][(dlo + 16) * 32 + 16 + lr] = a11[j];
  }
  __syncthreads();
  float* pp = part + ((size_t)sp * 32 + bh) * 1024;
  for (int idx = threadIdx.x; idx < 1024; idx += 256)
    pp[idx] = red[0][idx] + red[1][idx] + red[2][idx] + red[3][idx];
}

// ---------------- reduce ctx partials, apply 1/S, emit fp16 TRANSPOSED [e][d] ----------------
__global__ __launch_bounds__(256) void ctxred(const float* __restrict__ part,
                                              const float* __restrict__ Sk,
                                              half_t* __restrict__ ctxh) {
  int bh = blockIdx.x;
  int t = threadIdx.x;
  for (int idx = t; idx < 1024; idx += 256) {
    int d = idx >> 5, e = idx & 31;
    float s = 0.f;
#pragma unroll
    for (int sp = 0; sp < NSP; ++sp) s += part[((size_t)sp * 32 + bh) * 1024 + idx];
    ctxh[(size_t)bh * 1024 + e * 32 + d] = (half_t)(s / Sk[bh * HD + d]);
  }
}

// ---------------- attn5: P@ctx via MFMA; SiLU; swizzled LDS -> coalesced stores ----------------
// grid (HW/64, B), block 256 = 4 waves; wave w owns 16 px; all 8 heads.
// A-frag: P'[px=lr][d=lq*8+j] built in-register (no-max softmax, logits bounded).
// B-frag: ctxh[bh][e=lr(+16eh)][d=lq*8..+7] one f16x8 per frag, held in regs.
__global__ __launch_bounds__(256) void attn5(const half_t* __restrict__ Qh,
                                             const half_t* __restrict__ ctxh,
                                             half_t* __restrict__ Oh) {
  const int b = blockIdx.y;
  const int lane = threadIdx.x & 63;
  const int w = threadIdx.x >> 6;
  const int lr = lane & 15, lq = lane >> 4;
  const int px = blockIdx.x * 64 + w * 16 + lr;       // A-row pixel for this lane
  __shared__ half_t osm[64 * 256];                    // 32KB output tile [px][c] swizzled

  // B-fragments for all heads/e-halves (registers; fully static indexing)
  f16x8 cf[HEADS][2];
#pragma unroll
  for (int h = 0; h < HEADS; ++h)
#pragma unroll
    for (int eh = 0; eh < 2; ++eh)
      cf[h][eh] = *(const f16x8*)(ctxh + ((size_t)(b * HEADS + h)) * 1024
                                  + (eh * 16 + lr) * 32 + lq * 8);

  const int pxl_base = w * 16 + lq * 4;               // D-row local pixel base
#pragma unroll
  for (int h = 0; h < HEADS; ++h) {
    // build A-frag: 8 strided q loads, exp, cross-lane sum, scale, cvt fp16
    const half_t* qp = Qh + ((size_t)(b * C + h * HD + lq * 8)) * HW + px;
    float ev[8];
    float psum = 0.f;
#pragma unroll
    for (int j = 0; j < 8; ++j) {
      ev[j] = expf((float)qp[(size_t)j * HW]);        // no max pass: logits bounded
      psum += ev[j];
    }
    float s = psum;
    s += __shfl_xor(s, 16, 64);
    s += __shfl_xor(s, 32, 64);                       // sum over 4 lq groups (fixed lr)
    float inv = 0.1767766952966369f / s;              // 32^-0.5 / s
    f16x8 pa;
#pragma unroll
    for (int j = 0; j < 8; ++j) pa[j] = (half_t)(ev[j] * inv);

    f32x4 z = {0.f, 0.f, 0.f, 0.f};
    f32x4 a0 = __builtin_amdgcn_mfma_f32_16x16x32_f16(pa, cf[h][0], z, 0, 0, 0);
    f32x4 a1 = __builtin_amdgcn_mfma_f32_16x16x32_f16(pa, cf[h][1], z, 0, 0, 0);

    // epilogue: SiLU*OSCALE -> fp16 -> swizzled LDS [pxl][c]
#pragma unroll
    for (int eh = 0; eh < 2; ++eh) {
      f32x4 a = eh ? a1 : a0;
      int c = h * 32 + eh * 16 + lr;
#pragma unroll
      for (int j = 0; j < 4; ++j) {
        int pxl = pxl_base + j;                       // D row = lq*4+j
        float v = a[j];
        float sg = 1.f / (1.f + expf(-v));
        int byte = pxl * 512 + ((c * 2) ^ (((pxl >> 2) & 7) << 4));
        *(half_t*)((char*)osm + byte) = (half_t)(v * sg * OSCALE);
      }
    }
  }
  __syncthreads();

  // coalesced drain: 8 x f16x8 per thread
  half_t* ob = Oh + ((size_t)b * HW + blockIdx.x * 64) * 256;
#pragma unroll
  for (int it = 0; it < 8; ++it) {
    int i = it * 256 + threadIdx.x;                   // 16B-chunk index, 2048 total
    int pxl = i >> 5;
    int inrow = (i & 31) * 16;
    int src = pxl * 512 + (inrow ^ (((pxl >> 2) & 7) << 4));
    *(f16x8*)(ob + (size_t)pxl * 256 + inrow / 2) = *(const f16x8*)((const char*)osm + src);
  }
}

extern "C" void kernel_launch(void* const* d_in, const int* in_sizes, int n_in,
                              void* d_out, int out_size, void* d_ws, size_t ws_size,
                              hipStream_t stream) {
  const float* fmap = (const float*)d_in[0];
  const float* g    = (const float*)d_in[1];
  const float* wq1  = (const float*)d_in[2];
  const float* wq2  = (const float*)d_in[3];
  const float* wk1  = (const float*)d_in[4];
  const float* wk2  = (const float*)d_in[5];
  const float* wv1  = (const float*)d_in[6];
  const float* wv2  = (const float*)d_in[7];
  const float* wout = (const float*)d_in[8];
  float* out = (float*)d_out;
  char* ws = (char*)d_ws;

  const size_t SZ = (size_t)B * C * HW;
  const size_t Mi = (size_t)1 << 20;
  // layout (byte offsets), live ranges audited:
  half_t* Xh   = (half_t*)(ws);                  // [0,32Mi)    ln2 -> gemm<0>
  half_t* Yh   = (half_t*)(ws + 32 * Mi);        // [32,128Mi)  Yq|Yk|Yv fp16
  half_t* Qh   = (half_t*)(ws + 128 * Mi);       // [128,160Mi) dwQ -> attn5
  half_t* EK   = (half_t*)(ws);                  // [0,32Mi)    exp(k) fp16 (Xh dead)
  half_t* Vh   = (half_t*)out;                   // d_out as fp16 V until ctx_mfma done
  float*  part = (float*)(ws + 96 * Mi);         // [96,98Mi)   over dead Yv
  float*  Sk   = (float*)(ws + 99 * Mi);         // 4KB
  half_t* ctxh = (half_t*)(ws + 100 * Mi);       // 64KB fp16 transposed [bh][e][d]
  half_t* Wh   = (half_t*)(ws + 192 * Mi);
  half_t* Woh  = (half_t*)(ws + 192 * Mi + 512 * 1024);
  half_t* Oh   = (half_t*)(ws + 32 * Mi);        // over dead Yq

  wcvt_all<<<dim3(1024), 256, 0, stream>>>(wq1, wk1, wv1, wout, Wh, Woh);

  ln2<<<dim3(HW / 64, B), 256, 0, stream>>>(fmap, g, Xh);

  gemm16<0><<<dim3(HW / 128, 6, B), 256, 0, stream>>>(Xh, Wh, Yh, nullptr);

  dw3x3_v<1><<<dim3(Hh / 16, C, B), 256, 0, stream>>>(Yh, wq2, Qh);            // Q fp16
  dw3x3_v<2><<<dim3(Hh / 16, C, B), 256, 0, stream>>>(Yh + SZ, wk2, EK);       // exp(K) fp16
  dw3x3_v<1><<<dim3(Hh / 16, C, B), 256, 0, stream>>>(Yh + 2 * SZ, wv2, Vh);   // V fp16

  ksum<<<dim3(C, B), 256, 0, stream>>>(EK, Sk);

  ctx_mfma<<<dim3(HEADS * B, NSP), 256, 0, stream>>>(EK, Vh, part);
  ctxred<<<dim3(32), 256, 0, stream>>>(part, Sk, ctxh);

  attn5<<<dim3(HW / 64, B), 256, 0, stream>>>(Qh, ctxh, Oh);

  gemm16<1><<<dim3(HW / 128, 2, B), 256, 0, stream>>>(Oh, Woh, nullptr, out);
}